// Round 1
// baseline (853.775 us; speedup 1.0000x reference)
//
#include <hip/hip_runtime.h>

// FFM pairwise interaction:
//   out[b, p, e] = x[b,i,e] * x[b,j,e] * fe[i,j,e] * fe[j,i,e]
// for pairs p=(i,j), i<j in row-major triu order. B=4096, F=40, E=64, P=780.
// Memory-bound: 818 MB output write dominates. Strategy: 1 block per batch row,
// x row staged in LDS, fe read through L2 (0.4 MB, fully cache-resident),
// float4 everywhere (16 B/lane stores).

#define NF 40
#define NE 64
#define NP 780          // NF*(NF-1)/2
#define NPG 195         // NP/4 pair-groups (4 pairs per wave-iteration)

__global__ __launch_bounds__(256) void ffm_kernel(
    const float* __restrict__ x,
    const float* __restrict__ fe,
    float* __restrict__ out)
{
    __shared__ float xs[NF * NE];   // 10 KB: x[b, :, :]
    __shared__ int   pij[NP];       // 3.1 KB: packed (i<<8)|j per pair

    const int tid = threadIdx.x;
    const int b   = blockIdx.x;

    // Build pair-index table: thread i fills row i (pairs (i, i+1..39)).
    // base(i) = #pairs before row i = i*(2F-i-1)/2
    if (tid < NF - 1) {
        const int i = tid;
        const int base = i * (2 * NF - i - 1) / 2;
        for (int j = i + 1; j < NF; ++j)
            pij[base + (j - i - 1)] = (i << 8) | j;
    }

    // Stage x[b,:,:] (2560 floats) into LDS with float4 loads.
    const float4* xb4 = (const float4*)(x + (size_t)b * (NF * NE));
    float4* xs4 = (float4*)xs;
    for (int idx = tid; idx < NF * NE / 4; idx += 256) xs4[idx] = xb4[idx];

    __syncthreads();

    const int wave = tid >> 6;
    const int lane = tid & 63;
    const int e4   = lane & 15;   // which float4 of the 16 covering E=64
    const int psub = lane >> 4;   // which of the 4 pairs this wave handles per iter

    const float4* fe4 = (const float4*)fe;
    float4* ob4 = (float4*)(out + (size_t)b * (size_t)(NP * NE));

    for (int g = wave; g < NPG; g += 4) {
        const int p = g * 4 + psub;
        const int packed = pij[p];
        const int i = packed >> 8;
        const int j = packed & 255;

        const float4 xi  = xs4[i * 16 + e4];
        const float4 xj  = xs4[j * 16 + e4];
        const float4 fij = fe4[(i * NF + j) * 16 + e4];
        const float4 fji = fe4[(j * NF + i) * 16 + e4];

        float4 r;
        r.x = xi.x * xj.x * fij.x * fji.x;
        r.y = xi.y * xj.y * fij.y * fji.y;
        r.z = xi.z * xj.z * fij.z * fji.z;
        r.w = xi.w * xj.w * fij.w * fji.w;

        ob4[p * 16 + e4] = r;
    }
}

extern "C" void kernel_launch(void* const* d_in, const int* in_sizes, int n_in,
                              void* d_out, int out_size, void* d_ws, size_t ws_size,
                              hipStream_t stream) {
    const float* x  = (const float*)d_in[0];   // [B, 40, 64] fp32
    const float* fe = (const float*)d_in[1];   // [40, 40, 64] fp32
    float* out = (float*)d_out;                // [B, 780*64] fp32

    const int B = in_sizes[0] / (NF * NE);     // 4096
    ffm_kernel<<<dim3(B), dim3(256), 0, stream>>>(x, fe, out);
}